// Round 7
// baseline (3351.937 us; speedup 1.0000x reference)
//
#include <hip/hip_runtime.h>
#include <math.h>

#define NROWS 131072
#define DIMD  128
#define KCB   1024
#define NLEV  4
#define RB    32                 // rows per block (1 wave)
#define ACCEPT_EPS 1.0e-4f       // gap accept threshold; > 2*delta (delta~1.6e-5)

typedef __attribute__((ext_vector_type(8))) short short8;
typedef __attribute__((ext_vector_type(4))) float f32x4;

// d_ws layout (~2.1 MB, same as R6):
//   [0..16)    double lossAcc[2]
//   [16..16400) f32 e2g[4096]
//   hiT / loT: bf16 frag tables (pre-scaled x2), 1 MB each
#define WS_E2G   16
#define WS_HIT   16400
#define WS_LOT   (16400 + 1048576)

// numpy pairwise sumsq (AVX512 path) — validated R3/R5/R6. Do not reassociate.
__device__ __forceinline__ float np_sumsq128(const float* __restrict__ p) {
    float q[16];
    #pragma unroll
    for (int lane = 0; lane < 16; ++lane) {
        float c[8];
        #pragma unroll
        for (int j = 0; j < 8; ++j) { float v = p[16 * j + lane]; c[j] = v * v; }
        float s01 = c[0] + c[1], s23 = c[2] + c[3];
        float s45 = c[4] + c[5], s67 = c[6] + c[7];
        q[lane] = (s01 + s23) + (s45 + s67);
    }
    float t[8];
    #pragma unroll
    for (int j = 0; j < 8; ++j) t[j] = q[j] + q[j + 8];
    float u[4];
    #pragma unroll
    for (int j = 0; j < 4; ++j) u[j] = t[j] + t[j + 4];
    float w0 = u[0] + u[2], w1 = u[1] + u[3];
    return w0 + w1;
}

__device__ __forceinline__ short8 as_short8(uint4 u) {
    short8 v; __builtin_memcpy(&v, &u, 16); return v;
}

// gout = d_out. [0, N*D) doubles as the f32 residual buffer for levels 0..2
// (level 0 reads x); the level-3 epilogue overwrites it with the final out.
__global__ __launch_bounds__(64, 3)
void rvq_main(const float* __restrict__ x, const float* __restrict__ cb,
              float* gout, const float* __restrict__ e2g,
              const uint4* __restrict__ hiT, const uint4* __restrict__ loT,
              double* __restrict__ lossAcc)
{
    __shared__ unsigned long long bestS[RB];
    __shared__ float A_S[RB];
    __shared__ int   kminS[RB];
    __shared__ float devS[RB], swS[RB];
    __shared__ float commitS[RB], usageS[RB];
    __shared__ int   hardList[RB];
    __shared__ int   hardCnt;

    const int tid = threadIdx.x;                   // 0..63 (one wave)
    const int li  = tid & 15;                      // MFMA col-lane / dim-lane
    const int lg  = tid >> 4;                      // k-slice / row-group
    const int rowBase = blockIdx.x * RB;

    const float4* x4 = (const float4*)x;
    float4* g4 = (float4*)gout;

    if (tid < RB) { commitS[tid] = 0.0f; usageS[tid] = 0.0f; }

    for (int lev = 0; lev < NLEV; ++lev) {
        __syncthreads();
        const float*  rbase  = lev ? gout : x;     // residual rows for this level
        const float4* rbase4 = (const float4*)rbase;

        if (tid < RB) {
            A_S[tid]  = np_sumsq128(rbase + ((size_t)rowBase + tid) * DIMD);
            bestS[tid] = ~0ULL;
        }
        if (tid == 0) hardCnt = 0;

        const float* cbL  = cb  + (size_t)lev * KCB * DIMD;
        const float* e2gL = e2g + (size_t)lev * KCB;
        const uint4* hT = hiT + (size_t)lev * 16384;
        const uint4* lT = loT + (size_t)lev * 16384;

        // A fragments (bf16 hi/lo of 32 rows): lane holds A[row=16t+li][k=32ks+8lg+e]
        short8 aH[2][4], aL[2][4];
        #pragma unroll
        for (int t = 0; t < 2; ++t) {
            const float4* rp4 = rbase4 + ((size_t)rowBase + 16 * t + li) * 32;
            #pragma unroll
            for (int ks = 0; ks < 4; ++ks) {
                float4 p = rp4[8 * ks + 2 * lg];
                float4 q = rp4[8 * ks + 2 * lg + 1];
                uint4 uh, ul;
                float pv[8] = {p.x, p.y, p.z, p.w, q.x, q.y, q.z, q.w};
                unsigned hb[8]; float lv[8];
                #pragma unroll
                for (int e = 0; e < 8; ++e) {
                    unsigned b = __float_as_uint(pv[e]);
                    hb[e] = b & 0xFFFF0000u;
                    lv[e] = pv[e] - __uint_as_float(hb[e]);
                }
                uh.x = (hb[0] >> 16) | hb[1]; uh.y = (hb[2] >> 16) | hb[3];
                uh.z = (hb[4] >> 16) | hb[5]; uh.w = (hb[6] >> 16) | hb[7];
                ul.x = (__float_as_uint(lv[0]) >> 16) | (__float_as_uint(lv[1]) & 0xFFFF0000u);
                ul.y = (__float_as_uint(lv[2]) >> 16) | (__float_as_uint(lv[3]) & 0xFFFF0000u);
                ul.z = (__float_as_uint(lv[4]) >> 16) | (__float_as_uint(lv[5]) & 0xFFFF0000u);
                ul.w = (__float_as_uint(lv[6]) >> 16) | (__float_as_uint(lv[7]) & 0xFFFF0000u);
                aH[t][ks] = as_short8(uh);
                aL[t][ks] = as_short8(ul);
            }
        }

        float m1[8], m2[8], dev[8], swv[8];
        int   k1[8];
        #pragma unroll
        for (int s = 0; s < 8; ++s) {
            m1[s] = -__builtin_inff(); m2[s] = -__builtin_inff(); k1[s] = 0;
            dev[s] = 0.f; swv[s] = 0.f;
        }

        // per-cg: 24 MFMA + 16 score epilogues (sv = 2r·e − ||e||²; max-sv)
        auto compute_cg = [&](const uint4 (&hf)[4], const uint4 (&lf)[4], int cg) {
            short8 bH[4], bL[4];
            #pragma unroll
            for (int ks = 0; ks < 4; ++ks) { bH[ks] = as_short8(hf[ks]); bL[ks] = as_short8(lf[ks]); }
            f32x4 accH0 = {0.f,0.f,0.f,0.f}, accH1 = {0.f,0.f,0.f,0.f};
            f32x4 accA0 = {0.f,0.f,0.f,0.f}, accA1 = {0.f,0.f,0.f,0.f};
            f32x4 accB0 = {0.f,0.f,0.f,0.f}, accB1 = {0.f,0.f,0.f,0.f};
            #pragma unroll
            for (int ks = 0; ks < 4; ++ks) {       // 6 independent chains, depth 4
                accH0 = __builtin_amdgcn_mfma_f32_16x16x32_bf16(aH[0][ks], bH[ks], accH0, 0, 0, 0);
                accH1 = __builtin_amdgcn_mfma_f32_16x16x32_bf16(aH[1][ks], bH[ks], accH1, 0, 0, 0);
                accA0 = __builtin_amdgcn_mfma_f32_16x16x32_bf16(aH[0][ks], bL[ks], accA0, 0, 0, 0);
                accA1 = __builtin_amdgcn_mfma_f32_16x16x32_bf16(aH[1][ks], bL[ks], accA1, 0, 0, 0);
                accB0 = __builtin_amdgcn_mfma_f32_16x16x32_bf16(aL[0][ks], bH[ks], accB0, 0, 0, 0);
                accB1 = __builtin_amdgcn_mfma_f32_16x16x32_bf16(aL[1][ks], bH[ks], accB1, 0, 0, 0);
            }
            const float Cc = e2gL[cg * 16 + li];
            const int colg = cg * 16 + li;
            #pragma unroll
            for (int t = 0; t < 2; ++t) {
                #pragma unroll
                for (int r = 0; r < 4; ++r) {
                    const int s = 4 * t + r;
                    float b2 = t ? ((accH1[r] + accA1[r]) + accB1[r])
                                 : ((accH0[r] + accA0[r]) + accB0[r]);
                    float sv = b2 - Cc;
                    // top-2 (ties -> gap 0 -> hard-row fallback)
                    k1[s] = (sv > m1[s]) ? colg : k1[s];
                    m2[s] = __builtin_amdgcn_fmed3f(sv, m1[s], m2[s]);
                    m1[s] = fmaxf(m1[s], sv);
                    // stats: e-1 Sterbenz-exact for |sv|<=0.35
                    float e = __expf(sv);
                    dev[s] += (e - 1.0f);
                    swv[s]  = fmaf(sv, e, swv[s]);
                }
            }
        };

        // sweep 64 col-groups, register double-buffered global frag loads
        uint4 h0[4], l0[4], h1[4], l1[4];
        #pragma unroll
        for (int ks = 0; ks < 4; ++ks) { h0[ks] = hT[ks * 64 + tid]; l0[ks] = lT[ks * 64 + tid]; }
        for (int cg = 0; cg < 64; cg += 2) {
            #pragma unroll
            for (int ks = 0; ks < 4; ++ks) {
                h1[ks] = hT[(cg + 1) * 256 + ks * 64 + tid];
                l1[ks] = lT[(cg + 1) * 256 + ks * 64 + tid];
            }
            compute_cg(h0, l0, cg);
            if (cg + 2 < 64) {
                #pragma unroll
                for (int ks = 0; ks < 4; ++ks) {
                    h0[ks] = hT[(cg + 2) * 256 + ks * 64 + tid];
                    l0[ks] = lT[(cg + 2) * 256 + ks * 64 + tid];
                }
            }
            compute_cg(h1, l1, cg + 1);
        }

        // merge across the 16 lanes sharing rows
        #pragma unroll
        for (int s = 0; s < 8; ++s) {
            #pragma unroll
            for (int m = 8; m >= 1; m >>= 1) {
                float om1 = __shfl_xor(m1[s], m);
                float om2 = __shfl_xor(m2[s], m);
                int   ok1 = __shfl_xor(k1[s], m);
                float nm1, nm2; int nk1;
                if (om1 > m1[s])      { nm1 = om1;   nk1 = ok1;   nm2 = fmaxf(om2, m1[s]); }
                else if (om1 < m1[s]) { nm1 = m1[s]; nk1 = k1[s]; nm2 = fmaxf(m2[s], om1); }
                else                  { nm1 = m1[s]; nk1 = min(k1[s], ok1); nm2 = m1[s]; }
                m1[s] = nm1; m2[s] = nm2; k1[s] = nk1;
                dev[s] += __shfl_xor(dev[s], m);
                swv[s] += __shfl_xor(swv[s], m);
            }
        }
        if (li == 0) {
            #pragma unroll
            for (int t = 0; t < 2; ++t)
                #pragma unroll
                for (int r = 0; r < 4; ++r) {
                    const int s = 4 * t + r;
                    const int row = 16 * t + 4 * lg + r;
                    kminS[row] = k1[s];
                    devS[row]  = dev[s];
                    swS[row]   = swv[s];
                    if (!(m1[s] - m2[s] > ACCEPT_EPS)) {   // hard row
                        int p = atomicAdd(&hardCnt, 1);
                        hardList[p] = row;
                    }
                }
        }
        __syncthreads();

        // hard rows: exact fp32-replica scan over all 1024 k (R3-proven chain)
        const int nh = hardCnt;
        for (int h = 0; h < nh; ++h) {
            const int row = hardList[h];
            const float4* rrow4 = rbase4 + ((size_t)rowBase + row) * 32;  // broadcast
            const float Ar = A_S[row];
            unsigned long long best = ~0ULL;
            for (int kk = tid; kk < KCB; kk += 64) {
                const float4* ep4 = (const float4*)(cbL + (size_t)kk * DIMD);
                float b = 0.f;
                #pragma unroll 8
                for (int c4 = 0; c4 < 32; ++c4) {   // sequential ascending-d FMA
                    float4 ev = ep4[c4];
                    float4 rv = rrow4[c4];
                    b = fmaf(rv.x, ev.x, b);
                    b = fmaf(rv.y, ev.y, b);
                    b = fmaf(rv.z, ev.z, b);
                    b = fmaf(rv.w, ev.w, b);
                }
                float m2b = 2.0f * b;
                float t1  = Ar - m2b;
                float d32 = t1 + e2gL[kk];          // > 0 always (~128)
                unsigned long long pk =
                    ((unsigned long long)__float_as_uint(d32) << 32) | (unsigned)kk;
                if (pk < best) best = pk;
            }
            #pragma unroll
            for (int m = 32; m >= 1; m >>= 1) {
                unsigned long long o = __shfl_xor(best, m);
                if (o < best) best = o;
            }
            if (tid == 0) bestS[row] = best;
        }
        __syncthreads();

        // epilogue (R3/R6 validated): residual chain, codes, losses, out
        #pragma unroll
        for (int i = 0; i < 8; ++i) {
            const int row = 8 * lg + i;
            const size_t n = (size_t)rowBase + row;
            unsigned long long bs = bestS[row];
            const int bestk = (bs != ~0ULL) ? (int)(bs & 1023ULL) : kminS[row];

            const float4* q4p = (const float4*)(cbL + (size_t)bestk * DIMD);
            float4 qa = q4p[2 * li], qb = q4p[2 * li + 1];
            float4 ra = rbase4[n * 32 + 2 * li], rb = rbase4[n * 32 + 2 * li + 1];

            float nr0 = ra.x - qa.x, nr1 = ra.y - qa.y;
            float nr2 = ra.z - qa.z, nr3 = ra.w - qa.w;
            float nr4 = rb.x - qb.x, nr5 = rb.y - qb.y;
            float nr6 = rb.z - qb.z, nr7 = rb.w - qb.w;

            double cpart = 0.0;
            cpart += (double)(nr0 * nr0); cpart += (double)(nr1 * nr1);
            cpart += (double)(nr2 * nr2); cpart += (double)(nr3 * nr3);
            cpart += (double)(nr4 * nr4); cpart += (double)(nr5 * nr5);
            cpart += (double)(nr6 * nr6); cpart += (double)(nr7 * nr7);
            #pragma unroll
            for (int m = 8; m >= 1; m >>= 1) cpart += __shfl_xor(cpart, m);

            if (lev < NLEV - 1) {
                g4[n * 32 + 2 * li]     = make_float4(nr0, nr1, nr2, nr3);
                g4[n * 32 + 2 * li + 1] = make_float4(nr4, nr5, nr6, nr7);
            } else {
                float4 xa = x4[n * 32 + 2 * li];
                float4 xb = x4[n * 32 + 2 * li + 1];
                g4[n * 32 + 2 * li] = make_float4(
                    xa.x - nr0, xa.y - nr1, xa.z - nr2, xa.w - nr3);
                g4[n * 32 + 2 * li + 1] = make_float4(
                    xb.x - nr4, xb.y - nr5, xb.z - nr6, xb.w - nr7);
            }

            if (li == 0) {
                gout[(size_t)NROWS * DIMD + n * NLEV + lev] = (float)bestk;
                commitS[row] += (float)cpart;
                usageS[row]  += swS[row] / (1024.0f + devS[row])
                              - log1pf(devS[row] * (1.0f / 1024.0f));
            }
        }
    }

    __syncthreads();
    float u = 0.f, cm = 0.f;
    if (tid < RB) { u = usageS[tid]; cm = commitS[tid]; }
    #pragma unroll
    for (int m = 32; m >= 1; m >>= 1) { u += __shfl_xor(u, m); cm += __shfl_xor(cm, m); }
    if (tid == 0) {
        atomicAdd(&lossAcc[0], (double)cm);
        atomicAdd(&lossAcc[1], (double)u);
    }
}

// prep: loss reset, C = np_sumsq (ref-exact), bf16 hi/lo frag tables (pre-scaled x2)
__global__ void rvq_prep(const float* __restrict__ cb, float* __restrict__ e2g,
                         uint4* __restrict__ hiT, uint4* __restrict__ loT,
                         double* __restrict__ lossAcc)
{
    int idx = blockIdx.x * 256 + threadIdx.x;      // 0..65535
    if (idx == 0) { lossAcc[0] = 0.0; lossAcc[1] = 0.0; }
    if (idx < NLEV * KCB)
        e2g[idx] = np_sumsq128(cb + (size_t)idx * DIMD);

    int lev = idx >> 14, rem = idx & 16383;
    int cg = rem >> 8, ks = (rem >> 6) & 3, lane = rem & 63;
    int col = cg * 16 + (lane & 15);
    int k0  = ks * 32 + (lane >> 4) * 8;
    const float* src = cb + ((size_t)lev * KCB + col) * DIMD + k0;
    unsigned hb[8], lb[8];
    #pragma unroll
    for (int e = 0; e < 8; ++e) {
        float w = 2.0f * src[e];
        unsigned b = __float_as_uint(w);
        hb[e] = b >> 16;
        float lv = w - __uint_as_float(b & 0xFFFF0000u);
        lb[e] = __float_as_uint(lv) >> 16;
    }
    uint4 hp, lp;
    hp.x = hb[0] | (hb[1] << 16); hp.y = hb[2] | (hb[3] << 16);
    hp.z = hb[4] | (hb[5] << 16); hp.w = hb[6] | (hb[7] << 16);
    lp.x = lb[0] | (lb[1] << 16); lp.y = lb[2] | (lb[3] << 16);
    lp.z = lb[4] | (lb[5] << 16); lp.w = lb[6] | (lb[7] << 16);
    hiT[idx] = hp;
    loT[idx] = lp;
}

__global__ void rvq_fin(const double* __restrict__ lossAcc, float* __restrict__ out)
{
    out[(size_t)NROWS * DIMD + (size_t)NROWS * NLEV] =
        (float)(lossAcc[0] * (1.25 / ((double)NROWS * (double)DIMD)));
    out[(size_t)NROWS * DIMD + (size_t)NROWS * NLEV + 1] =
        (float)(lossAcc[1] / (double)NROWS);
}

extern "C" void kernel_launch(void* const* d_in, const int* in_sizes, int n_in,
                              void* d_out, int out_size, void* d_ws, size_t ws_size,
                              hipStream_t stream)
{
    const float* x  = (const float*)d_in[0];
    const float* cb = (const float*)d_in[1];
    float* out = (float*)d_out;
    double* lossAcc = (double*)d_ws;
    float* e2g = (float*)((char*)d_ws + WS_E2G);
    uint4* hiT = (uint4*)((char*)d_ws + WS_HIT);
    uint4* loT = (uint4*)((char*)d_ws + WS_LOT);

    rvq_prep<<<dim3(256), dim3(256), 0, stream>>>(cb, e2g, hiT, loT, lossAcc);
    rvq_main<<<dim3(NROWS / RB), dim3(64), 0, stream>>>(x, cb, out, e2g, hiT, loT, lossAcc);
    rvq_fin<<<dim3(1), dim3(1), 0, stream>>>(lossAcc, out);
}

// Round 8
// 1807.071 us; speedup vs baseline: 1.8549x; 1.8549x over previous
//
#include <hip/hip_runtime.h>
#include <math.h>

#define NROWS 131072
#define DIMD  128
#define KCB   1024
#define NLEV  4
#define ACCEPT_EPS 1.0e-4f       // gap accept; > 2*delta (delta ~2e-5 incl. drift)

typedef __attribute__((ext_vector_type(8))) short short8;
typedef __attribute__((ext_vector_type(4))) float f32x4;

// d_ws: [0,16) lossAcc, [16,16400) e2g[4096], then hi/lo bf16 frag tables (x2 scale)
#define WS_E2G   16
#define WS_HIT   16400
#define WS_LOT   (16400 + 1048576)

// numpy pairwise sumsq (AVX512 path) — validated R3/R5/R6. Do not reassociate.
__device__ __forceinline__ float np_sumsq128(const float* p) {
    float q[16];
    #pragma unroll
    for (int lane = 0; lane < 16; ++lane) {
        float c[8];
        #pragma unroll
        for (int j = 0; j < 8; ++j) { float v = p[16 * j + lane]; c[j] = v * v; }
        float s01 = c[0] + c[1], s23 = c[2] + c[3];
        float s45 = c[4] + c[5], s67 = c[6] + c[7];
        q[lane] = (s01 + s23) + (s45 + s67);
    }
    float t[8];
    #pragma unroll
    for (int j = 0; j < 8; ++j) t[j] = q[j] + q[j + 8];
    float u[4];
    #pragma unroll
    for (int j = 0; j < 4; ++j) u[j] = t[j] + t[j + 4];
    float w0 = u[0] + u[2], w1 = u[1] + u[3];
    return w0 + w1;
}

__device__ __forceinline__ short8 as_short8(uint4 u) {
    short8 v; __builtin_memcpy(&v, &u, 16); return v;
}
__device__ __forceinline__ float4 sub4(float4 a, float4 b) {
    return make_float4(a.x - b.x, a.y - b.y, a.z - b.z, a.w - b.w);
}
__device__ __forceinline__ void split_pair(float4 p, float4 q, short8& hi, short8& lo) {
    float pv[8] = {p.x, p.y, p.z, p.w, q.x, q.y, q.z, q.w};
    unsigned hb[8], lb[8];
    #pragma unroll
    for (int e = 0; e < 8; ++e) {
        unsigned b = __float_as_uint(pv[e]);
        hb[e] = b & 0xFFFF0000u;
        float lvf = pv[e] - __uint_as_float(hb[e]);   // exact
        lb[e] = __float_as_uint(lvf) & 0xFFFF0000u;
    }
    uint4 uh, ul;
    uh.x = (hb[0] >> 16) | hb[1]; uh.y = (hb[2] >> 16) | hb[3];
    uh.z = (hb[4] >> 16) | hb[5]; uh.w = (hb[6] >> 16) | hb[7];
    ul.x = (lb[0] >> 16) | lb[1]; ul.y = (lb[2] >> 16) | lb[3];
    ul.z = (lb[4] >> 16) | lb[5]; ul.w = (lb[6] >> 16) | lb[7];
    hi = as_short8(uh); lo = as_short8(ul);
}

__global__ __launch_bounds__(256, 3)
void rvq_main(const float* __restrict__ x, const float* __restrict__ cb,
              float* __restrict__ gout, const float* __restrict__ e2g,
              const uint4* __restrict__ hiT, const uint4* __restrict__ loT,
              double* __restrict__ lossAcc)
{
    __shared__ int    codesL[64][NLEV];
    __shared__ float  hardBuf[4][128];
    __shared__ double redBuf[4][2];

    const int tid = threadIdx.x;
    const int w   = tid >> 6;          // wave 0..3, owns rows [16w,16w+16) of block
    const int l   = tid & 63;
    const int li  = l & 15;
    const int lg  = l >> 4;
    const int rowW = blockIdx.x * 64 + w * 16;

    const float4* x4 = (const float4*)x;
    float4* g4 = (float4*)gout;

    // level-0 A fragments straight from x (lane: row rowW+li, k = 32ks+8lg+e)
    short8 aH[4], aL[4];
    #pragma unroll
    for (int ks = 0; ks < 4; ++ks) {
        float4 p = x4[(size_t)(rowW + li) * 32 + 8 * ks + 2 * lg];
        float4 q = x4[(size_t)(rowW + li) * 32 + 8 * ks + 2 * lg + 1];
        split_pair(p, q, aH[ks], aL[ks]);
    }

    float commitAcc = 0.f, usageAcc = 0.f;

    for (int lev = 0; lev < NLEV; ++lev) {
        const float*  cbL  = cb  + (size_t)lev * KCB * DIMD;
        const float4* cbL4 = (const float4*)cbL;
        const float*  e2gL = e2g + (size_t)lev * KCB;
        const uint4*  hT   = hiT + (size_t)lev * 16384;
        const uint4*  lT   = loT + (size_t)lev * 16384;

        float m1[4], m2[4], dev[4], sw[4];
        int   k1[4];
        #pragma unroll
        for (int s = 0; s < 4; ++s) {
            m1[s] = -__builtin_inff(); m2[s] = -__builtin_inff(); k1[s] = 0;
            dev[s] = 0.f; sw[s] = 0.f;
        }

        // per-cg: 12 MFMA (3 splits x 4 k-slices) + 4 score epilogues
        auto compute_cg = [&](const uint4 (&hf)[4], const uint4 (&lf)[4],
                              int cg, float Ccv) {
            short8 bH[4], bL[4];
            #pragma unroll
            for (int ks = 0; ks < 4; ++ks) { bH[ks] = as_short8(hf[ks]); bL[ks] = as_short8(lf[ks]); }
            f32x4 accH = {0.f,0.f,0.f,0.f}, accA = {0.f,0.f,0.f,0.f}, accB = {0.f,0.f,0.f,0.f};
            #pragma unroll
            for (int ks = 0; ks < 4; ++ks) {
                accH = __builtin_amdgcn_mfma_f32_16x16x32_bf16(aH[ks], bH[ks], accH, 0, 0, 0);
                accA = __builtin_amdgcn_mfma_f32_16x16x32_bf16(aH[ks], bL[ks], accA, 0, 0, 0);
                accB = __builtin_amdgcn_mfma_f32_16x16x32_bf16(aL[ks], bH[ks], accB, 0, 0, 0);
            }
            const int colg = cg * 16 + li;
            #pragma unroll
            for (int r = 0; r < 4; ++r) {
                float b2 = (accH[r] + accA[r]) + accB[r];
                float sv = b2 - Ccv;
                k1[r] = (sv > m1[r]) ? colg : k1[r];
                m2[r] = __builtin_amdgcn_fmed3f(sv, m1[r], m2[r]);
                m1[r] = fmaxf(m1[r], sv);
                float e = __expf(sv);             // |sv|<~0.2: e-1 Sterbenz-exact
                dev[r] += (e - 1.0f);
                sw[r]   = fmaf(sv, e, sw[r]);
            }
        };

        // sweep 64 cgs; b-frag addrs identical across waves -> phase-lock for L1 reuse
        uint4 h0[4], l0[4], h1[4], l1[4];
        float c0 = e2gL[li], c1;
        #pragma unroll
        for (int ks = 0; ks < 4; ++ks) { h0[ks] = hT[ks * 64 + l]; l0[ks] = lT[ks * 64 + l]; }
        for (int cg = 0; cg < 64; cg += 2) {
            __builtin_amdgcn_s_barrier();          // raw: no vmcnt drain, keeps prefetch
            #pragma unroll
            for (int ks = 0; ks < 4; ++ks) {
                h1[ks] = hT[(cg + 1) * 256 + ks * 64 + l];
                l1[ks] = lT[(cg + 1) * 256 + ks * 64 + l];
            }
            c1 = e2gL[(cg + 1) * 16 + li];
            compute_cg(h0, l0, cg, c0);
            if (cg + 2 < 64) {
                #pragma unroll
                for (int ks = 0; ks < 4; ++ks) {
                    h0[ks] = hT[(cg + 2) * 256 + ks * 64 + l];
                    l0[ks] = lT[(cg + 2) * 256 + ks * 64 + l];
                }
                c0 = e2gL[(cg + 2) * 16 + li];
            }
            compute_cg(h1, l1, cg + 1, c1);
        }

        // merge over the 16 li-lanes (rows 4lg+s of this wave)
        #pragma unroll
        for (int s = 0; s < 4; ++s) {
            #pragma unroll
            for (int m = 8; m >= 1; m >>= 1) {
                float om1 = __shfl_xor(m1[s], m);
                float om2 = __shfl_xor(m2[s], m);
                int   ok1 = __shfl_xor(k1[s], m);
                float nm1, nm2; int nk1;
                if (om1 > m1[s])      { nm1 = om1;   nk1 = ok1;   nm2 = fmaxf(om2, m1[s]); }
                else if (om1 < m1[s]) { nm1 = m1[s]; nk1 = k1[s]; nm2 = fmaxf(m2[s], om1); }
                else                  { nm1 = m1[s]; nk1 = min(k1[s], ok1); nm2 = m1[s]; }
                m1[s] = nm1; m2[s] = nm2; k1[s] = nk1;
                dev[s] += __shfl_xor(dev[s], m);
                sw[s]  += __shfl_xor(sw[s], m);
            }
        }

        // hard detection via ballots (no LDS counters); owners write provisional codes
        unsigned long long hm[4];
        #pragma unroll
        for (int s = 0; s < 4; ++s)
            hm[s] = __ballot((li == 0) && !(m1[s] - m2[s] > ACCEPT_EPS));
        if (li == 0) {
            #pragma unroll
            for (int s = 0; s < 4; ++s) {
                codesL[w * 16 + 4 * lg + s][lev] = k1[s];
                usageAcc += sw[s] / (1024.0f + dev[s])
                          - log1pf(dev[s] * (1.0f / 1024.0f));
            }
        }
        __threadfence_block();

        // hard rows: exact fp32-replica scan (R3-proven chain), whole wave per row
        #pragma unroll
        for (int s = 0; s < 4; ++s) {
            unsigned long long ms = hm[s];
            while (ms) {
                int b = __builtin_ctzll(ms); ms &= ms - 1;
                const int rowl = 4 * (b >> 4) + s;            // wave-local row
                if (li == rowl) {                              // 4 lanes: exact chain to lev-1
                    float4 v[8];
                    #pragma unroll
                    for (int ks = 0; ks < 4; ++ks) {
                        v[2 * ks]     = x4[(size_t)(rowW + rowl) * 32 + 8 * ks + 2 * lg];
                        v[2 * ks + 1] = x4[(size_t)(rowW + rowl) * 32 + 8 * ks + 2 * lg + 1];
                    }
                    for (int l2 = 0; l2 < lev; ++l2) {
                        int c = codesL[w * 16 + rowl][l2];
                        const float4* q4 = (const float4*)(cb + ((size_t)l2 * KCB + c) * DIMD);
                        #pragma unroll
                        for (int ks = 0; ks < 4; ++ks) {
                            v[2 * ks]     = sub4(v[2 * ks],     q4[8 * ks + 2 * lg]);
                            v[2 * ks + 1] = sub4(v[2 * ks + 1], q4[8 * ks + 2 * lg + 1]);
                        }
                    }
                    #pragma unroll
                    for (int ks = 0; ks < 4; ++ks) {
                        ((float4*)hardBuf[w])[8 * ks + 2 * lg]     = v[2 * ks];
                        ((float4*)hardBuf[w])[8 * ks + 2 * lg + 1] = v[2 * ks + 1];
                    }
                }
                __threadfence_block();
                float Ar = np_sumsq128(&hardBuf[w][0]);        // np-tree (redundant per lane)
                unsigned long long best = ~0ULL;
                const float4* rr4 = (const float4*)hardBuf[w];
                #pragma unroll 1
                for (int i = 0; i < 16; ++i) {
                    int kk = i * 64 + l;
                    const float4* ep4 = cbL4 + (size_t)kk * 32;
                    float bsum = 0.f;
                    #pragma unroll 8
                    for (int c4 = 0; c4 < 32; ++c4) {          // sequential ascending-d FMA
                        float4 ev = ep4[c4], rv = rr4[c4];
                        bsum = fmaf(rv.x, ev.x, bsum);
                        bsum = fmaf(rv.y, ev.y, bsum);
                        bsum = fmaf(rv.z, ev.z, bsum);
                        bsum = fmaf(rv.w, ev.w, bsum);
                    }
                    float m2b = 2.0f * bsum;
                    float t1  = Ar - m2b;
                    float d32 = t1 + e2gL[kk];                 // > 0 (~128)
                    unsigned long long pk =
                        ((unsigned long long)__float_as_uint(d32) << 32) | (unsigned)kk;
                    if (pk < best) best = pk;
                }
                #pragma unroll
                for (int m = 32; m >= 1; m >>= 1) {
                    unsigned long long o = __shfl_xor(best, m);
                    if (o < best) best = o;
                }
                if (l == 0) codesL[w * 16 + rowl][lev] = (int)(best & 1023ULL);
                __threadfence_block();
            }
        }
        __threadfence_block();

        // epilogue: exact f32 chain from x + codes (commit, codes-out, next A / out)
        {
            float4 v[8];
            #pragma unroll
            for (int ks = 0; ks < 4; ++ks) {
                v[2 * ks]     = x4[(size_t)(rowW + li) * 32 + 8 * ks + 2 * lg];
                v[2 * ks + 1] = x4[(size_t)(rowW + li) * 32 + 8 * ks + 2 * lg + 1];
            }
            for (int l2 = 0; l2 <= lev; ++l2) {
                int c = codesL[w * 16 + li][l2];
                const float4* q4 = (const float4*)(cb + ((size_t)l2 * KCB + c) * DIMD);
                #pragma unroll
                for (int ks = 0; ks < 4; ++ks) {
                    v[2 * ks]     = sub4(v[2 * ks],     q4[8 * ks + 2 * lg]);
                    v[2 * ks + 1] = sub4(v[2 * ks + 1], q4[8 * ks + 2 * lg + 1]);
                }
            }
            float cp = 0.f;
            #pragma unroll
            for (int j = 0; j < 8; ++j) {
                cp = fmaf(v[j].x, v[j].x, cp); cp = fmaf(v[j].y, v[j].y, cp);
                cp = fmaf(v[j].z, v[j].z, cp); cp = fmaf(v[j].w, v[j].w, cp);
            }
            cp += __shfl_xor(cp, 16); cp += __shfl_xor(cp, 32);
            if (lg == 0) {
                commitAcc += cp;
                gout[(size_t)NROWS * DIMD + (size_t)(rowW + li) * NLEV + lev] =
                    (float)codesL[w * 16 + li][lev];
            }
            if (lev < NLEV - 1) {
                #pragma unroll
                for (int ks = 0; ks < 4; ++ks)
                    split_pair(v[2 * ks], v[2 * ks + 1], aH[ks], aL[ks]);
            } else {
                #pragma unroll
                for (int ks = 0; ks < 4; ++ks) {
                    float4 xa = x4[(size_t)(rowW + li) * 32 + 8 * ks + 2 * lg];
                    float4 xb = x4[(size_t)(rowW + li) * 32 + 8 * ks + 2 * lg + 1];
                    g4[(size_t)(rowW + li) * 32 + 8 * ks + 2 * lg]     = sub4(xa, v[2 * ks]);
                    g4[(size_t)(rowW + li) * 32 + 8 * ks + 2 * lg + 1] = sub4(xb, v[2 * ks + 1]);
                }
            }
        }
    }

    // block loss reduction: one atomic pair per block
    float cm = (lg == 0) ? commitAcc : 0.f;
    float uu = (li == 0) ? usageAcc : 0.f;
    #pragma unroll
    for (int m = 32; m >= 1; m >>= 1) { cm += __shfl_xor(cm, m); uu += __shfl_xor(uu, m); }
    if (l == 0) { redBuf[w][0] = (double)cm; redBuf[w][1] = (double)uu; }
    __syncthreads();
    if (tid == 0) {
        double c = redBuf[0][0] + redBuf[1][0] + redBuf[2][0] + redBuf[3][0];
        double u = redBuf[0][1] + redBuf[1][1] + redBuf[2][1] + redBuf[3][1];
        atomicAdd(&lossAcc[0], c);
        atomicAdd(&lossAcc[1], u);
    }
}

// prep: loss reset, C = np_sumsq (ref-exact), bf16 hi/lo frag tables (pre-scaled x2)
__global__ void rvq_prep(const float* __restrict__ cb, float* __restrict__ e2g,
                         uint4* __restrict__ hiT, uint4* __restrict__ loT,
                         double* __restrict__ lossAcc)
{
    int idx = blockIdx.x * 256 + threadIdx.x;      // 0..65535
    if (idx == 0) { lossAcc[0] = 0.0; lossAcc[1] = 0.0; }
    if (idx < NLEV * KCB)
        e2g[idx] = np_sumsq128(cb + (size_t)idx * DIMD);

    int lev = idx >> 14, rem = idx & 16383;
    int cg = rem >> 8, ks = (rem >> 6) & 3, lane = rem & 63;
    int col = cg * 16 + (lane & 15);
    int k0  = ks * 32 + (lane >> 4) * 8;
    const float* src = cb + ((size_t)lev * KCB + col) * DIMD + k0;
    unsigned hb[8], lb[8];
    #pragma unroll
    for (int e = 0; e < 8; ++e) {
        float wv = 2.0f * src[e];                  // exact scale
        unsigned b = __float_as_uint(wv);
        hb[e] = b >> 16;
        float lv = wv - __uint_as_float(b & 0xFFFF0000u);
        lb[e] = __float_as_uint(lv) >> 16;
    }
    uint4 hp, lp;
    hp.x = hb[0] | (hb[1] << 16); hp.y = hb[2] | (hb[3] << 16);
    hp.z = hb[4] | (hb[5] << 16); hp.w = hb[6] | (hb[7] << 16);
    lp.x = lb[0] | (lb[1] << 16); lp.y = lb[2] | (lb[3] << 16);
    lp.z = lb[4] | (lb[5] << 16); lp.w = lb[6] | (lb[7] << 16);
    hiT[idx] = hp;
    loT[idx] = lp;
}

__global__ void rvq_fin(const double* __restrict__ lossAcc, float* __restrict__ out)
{
    out[(size_t)NROWS * DIMD + (size_t)NROWS * NLEV] =
        (float)(lossAcc[0] * (1.25 / ((double)NROWS * (double)DIMD)));
    out[(size_t)NROWS * DIMD + (size_t)NROWS * NLEV + 1] =
        (float)(lossAcc[1] / (double)NROWS);
}

extern "C" void kernel_launch(void* const* d_in, const int* in_sizes, int n_in,
                              void* d_out, int out_size, void* d_ws, size_t ws_size,
                              hipStream_t stream)
{
    const float* x  = (const float*)d_in[0];
    const float* cb = (const float*)d_in[1];
    float* out = (float*)d_out;
    double* lossAcc = (double*)d_ws;
    float* e2g = (float*)((char*)d_ws + WS_E2G);
    uint4* hiT = (uint4*)((char*)d_ws + WS_HIT);
    uint4* loT = (uint4*)((char*)d_ws + WS_LOT);

    rvq_prep<<<dim3(256), dim3(256), 0, stream>>>(cb, e2g, hiT, loT, lossAcc);
    rvq_main<<<dim3(NROWS / 64), dim3(256), 0, stream>>>(x, cb, out, e2g, hiT, loT, lossAcc);
    rvq_fin<<<dim3(1), dim3(1), 0, stream>>>(lossAcc, out);
}

// Round 9
// 1720.822 us; speedup vs baseline: 1.9479x; 1.0501x over previous
//
#include <hip/hip_runtime.h>
#include <math.h>

#define NROWS 131072
#define DIMD  128
#define KCB   1024
#define NLEV  4
#define ACCEPT_EPS 1.0e-4f       // gap accept; > 2*delta (delta ~2e-5 incl. drift)

typedef __attribute__((ext_vector_type(8))) short short8;
typedef __attribute__((ext_vector_type(4))) float f32x4;

// d_ws: [0,16) lossAcc, [16,16400) e2g[4096], then hi/lo bf16 frag tables (x2 scale)
#define WS_E2G   16
#define WS_HIT   16400
#define WS_LOT   (16400 + 1048576)

#define GLOAD_LDS16(g, s)                                                      \
    __builtin_amdgcn_global_load_lds(                                          \
        (const __attribute__((address_space(1))) void*)(g),                    \
        (__attribute__((address_space(3))) void*)(s), 16, 0, 0)

// numpy pairwise sumsq (AVX512 path) — validated R3/R5/R6/R8. Do not reassociate.
__device__ __forceinline__ float np_sumsq128(const float* p) {
    float q[16];
    #pragma unroll
    for (int lane = 0; lane < 16; ++lane) {
        float c[8];
        #pragma unroll
        for (int j = 0; j < 8; ++j) { float v = p[16 * j + lane]; c[j] = v * v; }
        float s01 = c[0] + c[1], s23 = c[2] + c[3];
        float s45 = c[4] + c[5], s67 = c[6] + c[7];
        q[lane] = (s01 + s23) + (s45 + s67);
    }
    float t[8];
    #pragma unroll
    for (int j = 0; j < 8; ++j) t[j] = q[j] + q[j + 8];
    float u[4];
    #pragma unroll
    for (int j = 0; j < 4; ++j) u[j] = t[j] + t[j + 4];
    float w0 = u[0] + u[2], w1 = u[1] + u[3];
    return w0 + w1;
}

__device__ __forceinline__ short8 as_short8(uint4 u) {
    short8 v; __builtin_memcpy(&v, &u, 16); return v;
}
__device__ __forceinline__ float4 sub4(float4 a, float4 b) {
    return make_float4(a.x - b.x, a.y - b.y, a.z - b.z, a.w - b.w);
}
__device__ __forceinline__ void split_pair(float4 p, float4 q, short8& hi, short8& lo) {
    float pv[8] = {p.x, p.y, p.z, p.w, q.x, q.y, q.z, q.w};
    unsigned hb[8], lb[8];
    #pragma unroll
    for (int e = 0; e < 8; ++e) {
        unsigned b = __float_as_uint(pv[e]);
        hb[e] = b & 0xFFFF0000u;
        float lvf = pv[e] - __uint_as_float(hb[e]);   // exact
        lb[e] = __float_as_uint(lvf) & 0xFFFF0000u;
    }
    uint4 uh, ul;
    uh.x = (hb[0] >> 16) | hb[1]; uh.y = (hb[2] >> 16) | hb[3];
    uh.z = (hb[4] >> 16) | hb[5]; uh.w = (hb[6] >> 16) | hb[7];
    ul.x = (lb[0] >> 16) | lb[1]; ul.y = (lb[2] >> 16) | lb[3];
    ul.z = (lb[4] >> 16) | lb[5]; ul.w = (lb[6] >> 16) | lb[7];
    hi = as_short8(uh); lo = as_short8(ul);
}

__global__ __launch_bounds__(256, 2)
void rvq_main(const float* __restrict__ x, const float* __restrict__ cb,
              float* __restrict__ gout, const float* __restrict__ e2g,
              const uint4* __restrict__ hiT, const uint4* __restrict__ loT,
              double* __restrict__ lossAcc)
{
    __shared__ uint4  bbuf[2][512];        // [buf][chunk j*64 + lane], 8 KB each
    __shared__ int    codesL[128][NLEV];
    __shared__ float  hardBuf[4][128];
    __shared__ double redBuf[4][2];

    const int tid = threadIdx.x;
    const int w   = tid >> 6;              // wave 0..3: rows [32w, 32w+32) of block
    const int l   = tid & 63;
    const int li  = l & 15;
    const int lg  = l >> 4;
    const int rowW = blockIdx.x * 128 + w * 32;

    const float4* x4 = (const float4*)x;
    float4* g4 = (float4*)gout;

    // level-0 A fragments from x: tile t row rowW+16t+li, k = 32ks+8lg+e
    short8 aH[2][4], aL[2][4];
    #pragma unroll
    for (int t = 0; t < 2; ++t)
        #pragma unroll
        for (int ks = 0; ks < 4; ++ks) {
            float4 p = x4[(size_t)(rowW + 16 * t + li) * 32 + 8 * ks + 2 * lg];
            float4 q = x4[(size_t)(rowW + 16 * t + li) * 32 + 8 * ks + 2 * lg + 1];
            split_pair(p, q, aH[t][ks], aL[t][ks]);
        }

    float commitAcc = 0.f, usageAcc = 0.f;

    for (int lev = 0; lev < NLEV; ++lev) {
        const float*  cbL  = cb  + (size_t)lev * KCB * DIMD;
        const float4* cbL4 = (const float4*)cbL;
        const float*  e2gL = e2g + (size_t)lev * KCB;
        const uint4*  hT   = hiT + (size_t)lev * 16384;
        const uint4*  lT   = loT + (size_t)lev * 16384;

        __syncthreads();                   // prior level fully done
        // prologue: stage cg0 into buf 0 (wave w stages chunks 2w, 2w+1)
        #pragma unroll
        for (int jj = 0; jj < 2; ++jj) {
            const int j = 2 * w + jj;
            const uint4* src = (j < 4 ? hT + j * 64 : lT + (j - 4) * 64) + l;
            GLOAD_LDS16(src, &bbuf[0][j * 64]);
        }

        float m1[8], m2[8], dev[8], sw[8];
        int   k1[8];
        #pragma unroll
        for (int s = 0; s < 8; ++s) {
            m1[s] = -__builtin_inff(); m2[s] = -__builtin_inff(); k1[s] = 0;
            dev[s] = 0.f; sw[s] = 0.f;
        }
        __syncthreads();                   // buf0 staged (vmcnt drained per wave)

        int cur = 0;
        for (int cg = 0; cg < 64; ++cg) {
            // issue next-tile staging (never drains mid-loop; T3 2-phase)
            if (cg + 1 < 64) {
                #pragma unroll
                for (int jj = 0; jj < 2; ++jj) {
                    const int j = 2 * w + jj;
                    const uint4* src = (j < 4 ? hT + (size_t)(cg + 1) * 256 + j * 64
                                              : lT + (size_t)(cg + 1) * 256 + (j - 4) * 64) + l;
                    GLOAD_LDS16(src, &bbuf[cur ^ 1][j * 64]);
                }
            }
            // B frags from LDS (stride-16 b128: conflict-free)
            short8 bH[4], bL[4];
            #pragma unroll
            for (int ks = 0; ks < 4; ++ks) {
                bH[ks] = *(const short8*)&bbuf[cur][ks * 64 + l];
                bL[ks] = *(const short8*)&bbuf[cur][(4 + ks) * 64 + l];
            }
            const float Cc   = e2gL[cg * 16 + li];
            const int   colg = cg * 16 + li;
            #pragma unroll
            for (int t = 0; t < 2; ++t) {
                f32x4 accH = {0.f,0.f,0.f,0.f}, accA = {0.f,0.f,0.f,0.f}, accB = {0.f,0.f,0.f,0.f};
                #pragma unroll
                for (int ks = 0; ks < 4; ++ks) {
                    accH = __builtin_amdgcn_mfma_f32_16x16x32_bf16(aH[t][ks], bH[ks], accH, 0, 0, 0);
                    accA = __builtin_amdgcn_mfma_f32_16x16x32_bf16(aH[t][ks], bL[ks], accA, 0, 0, 0);
                    accB = __builtin_amdgcn_mfma_f32_16x16x32_bf16(aL[t][ks], bH[ks], accB, 0, 0, 0);
                }
                #pragma unroll
                for (int r = 0; r < 4; ++r) {
                    const int s = 4 * t + r;
                    float b2 = (accH[r] + accA[r]) + accB[r];
                    float sv = b2 - Cc;                       // ~ A - d32 (shifted)
                    k1[s] = (sv > m1[s]) ? colg : k1[s];
                    m2[s] = __builtin_amdgcn_fmed3f(sv, m1[s], m2[s]);
                    m1[s] = fmaxf(m1[s], sv);
                    float e = __expf(sv);                     // |sv|<~0.35
                    dev[s] += (e - 1.0f);                     // Sterbenz-exact
                    sw[s]   = fmaf(sv, e, sw[s]);
                }
            }
            __syncthreads();               // own staging loads drained; buf swap safe
            cur ^= 1;
        }

        // merge over the 16 li-lanes (rows 16t+4lg+r of this wave)
        #pragma unroll
        for (int s = 0; s < 8; ++s) {
            #pragma unroll
            for (int m = 8; m >= 1; m >>= 1) {
                float om1 = __shfl_xor(m1[s], m);
                float om2 = __shfl_xor(m2[s], m);
                int   ok1 = __shfl_xor(k1[s], m);
                float nm1, nm2; int nk1;
                if (om1 > m1[s])      { nm1 = om1;   nk1 = ok1;   nm2 = fmaxf(om2, m1[s]); }
                else if (om1 < m1[s]) { nm1 = m1[s]; nk1 = k1[s]; nm2 = fmaxf(m2[s], om1); }
                else                  { nm1 = m1[s]; nk1 = min(k1[s], ok1); nm2 = m1[s]; }
                m1[s] = nm1; m2[s] = nm2; k1[s] = nk1;
                dev[s] += __shfl_xor(dev[s], m);
                sw[s]  += __shfl_xor(sw[s], m);
            }
        }

        // hard detection via ballots; li==0 owners write provisional codes + usage
        unsigned long long hm[8];
        #pragma unroll
        for (int s = 0; s < 8; ++s)
            hm[s] = __ballot((li == 0) && !(m1[s] - m2[s] > ACCEPT_EPS));
        if (li == 0) {
            #pragma unroll
            for (int s = 0; s < 8; ++s) {
                codesL[32 * w + 16 * (s >> 2) + 4 * lg + (s & 3)][lev] = k1[s];
                usageAcc += sw[s] / (1024.0f + dev[s])
                          - log1pf(dev[s] * (1.0f / 1024.0f));
            }
        }
        __threadfence_block();

        // hard rows: exact fp32-replica scan (R3-proven chain), whole wave per row
        #pragma unroll
        for (int s = 0; s < 8; ++s) {
            unsigned long long ms = hm[s];
            while (ms) {
                int b = __builtin_ctzll(ms); ms &= ms - 1;
                const int rowl = 16 * (s >> 2) + 4 * (b >> 4) + (s & 3);  // 0..31
                if (li == (rowl & 15)) {           // 4 producer lanes (lg 0..3)
                    float4 v[8];
                    #pragma unroll
                    for (int ks = 0; ks < 4; ++ks) {
                        v[2 * ks]     = x4[(size_t)(rowW + rowl) * 32 + 8 * ks + 2 * lg];
                        v[2 * ks + 1] = x4[(size_t)(rowW + rowl) * 32 + 8 * ks + 2 * lg + 1];
                    }
                    for (int l2 = 0; l2 < lev; ++l2) {
                        int c = codesL[32 * w + rowl][l2];
                        const float4* q4 = (const float4*)(cb + ((size_t)l2 * KCB + c) * DIMD);
                        #pragma unroll
                        for (int ks = 0; ks < 4; ++ks) {
                            v[2 * ks]     = sub4(v[2 * ks],     q4[8 * ks + 2 * lg]);
                            v[2 * ks + 1] = sub4(v[2 * ks + 1], q4[8 * ks + 2 * lg + 1]);
                        }
                    }
                    #pragma unroll
                    for (int ks = 0; ks < 4; ++ks) {
                        ((float4*)hardBuf[w])[8 * ks + 2 * lg]     = v[2 * ks];
                        ((float4*)hardBuf[w])[8 * ks + 2 * lg + 1] = v[2 * ks + 1];
                    }
                }
                __threadfence_block();
                float Ar = np_sumsq128(&hardBuf[w][0]);
                unsigned long long best = ~0ULL;
                const float4* rr4 = (const float4*)hardBuf[w];
                #pragma unroll 1
                for (int i = 0; i < 16; ++i) {
                    int kk = i * 64 + l;
                    const float4* ep4 = cbL4 + (size_t)kk * 32;
                    float bsum = 0.f;
                    #pragma unroll 8
                    for (int c4 = 0; c4 < 32; ++c4) {     // sequential ascending-d FMA
                        float4 ev = ep4[c4], rv = rr4[c4];
                        bsum = fmaf(rv.x, ev.x, bsum);
                        bsum = fmaf(rv.y, ev.y, bsum);
                        bsum = fmaf(rv.z, ev.z, bsum);
                        bsum = fmaf(rv.w, ev.w, bsum);
                    }
                    float m2b = 2.0f * bsum;
                    float t1  = Ar - m2b;
                    float d32 = t1 + e2gL[kk];            // > 0 (~128)
                    unsigned long long pk =
                        ((unsigned long long)__float_as_uint(d32) << 32) | (unsigned)kk;
                    if (pk < best) best = pk;
                }
                #pragma unroll
                for (int m = 32; m >= 1; m >>= 1) {
                    unsigned long long o = __shfl_xor(best, m);
                    if (o < best) best = o;
                }
                if (l == 0) codesL[32 * w + rowl][lev] = (int)(best & 1023ULL);
                __threadfence_block();
            }
        }
        __threadfence_block();

        // epilogue: exact f32 chain from x + codes (commit, codes-out, next A / out)
        #pragma unroll
        for (int t = 0; t < 2; ++t) {
            const int rloc = 32 * w + 16 * t + li;
            const size_t n = (size_t)rowW + 16 * t + li;
            float4 v[8];
            #pragma unroll
            for (int ks = 0; ks < 4; ++ks) {
                v[2 * ks]     = x4[n * 32 + 8 * ks + 2 * lg];
                v[2 * ks + 1] = x4[n * 32 + 8 * ks + 2 * lg + 1];
            }
            for (int l2 = 0; l2 <= lev; ++l2) {
                int c = codesL[rloc][l2];
                const float4* q4 = (const float4*)(cb + ((size_t)l2 * KCB + c) * DIMD);
                #pragma unroll
                for (int ks = 0; ks < 4; ++ks) {
                    v[2 * ks]     = sub4(v[2 * ks],     q4[8 * ks + 2 * lg]);
                    v[2 * ks + 1] = sub4(v[2 * ks + 1], q4[8 * ks + 2 * lg + 1]);
                }
            }
            float cp = 0.f;
            #pragma unroll
            for (int j = 0; j < 8; ++j) {
                cp = fmaf(v[j].x, v[j].x, cp); cp = fmaf(v[j].y, v[j].y, cp);
                cp = fmaf(v[j].z, v[j].z, cp); cp = fmaf(v[j].w, v[j].w, cp);
            }
            cp += __shfl_xor(cp, 16); cp += __shfl_xor(cp, 32);
            if (lg == 0) {
                commitAcc += cp;
                gout[(size_t)NROWS * DIMD + n * NLEV + lev] = (float)codesL[rloc][lev];
            }
            if (lev < NLEV - 1) {
                #pragma unroll
                for (int ks = 0; ks < 4; ++ks)
                    split_pair(v[2 * ks], v[2 * ks + 1], aH[t][ks], aL[t][ks]);
            } else {
                #pragma unroll
                for (int ks = 0; ks < 4; ++ks) {
                    float4 xa = x4[n * 32 + 8 * ks + 2 * lg];
                    float4 xb = x4[n * 32 + 8 * ks + 2 * lg + 1];
                    g4[n * 32 + 8 * ks + 2 * lg]     = sub4(xa, v[2 * ks]);
                    g4[n * 32 + 8 * ks + 2 * lg + 1] = sub4(xb, v[2 * ks + 1]);
                }
            }
        }
    }

    // block loss reduction: one atomic pair per block
    float cm = (lg == 0) ? commitAcc : 0.f;
    float uu = (li == 0) ? usageAcc : 0.f;
    #pragma unroll
    for (int m = 32; m >= 1; m >>= 1) { cm += __shfl_xor(cm, m); uu += __shfl_xor(uu, m); }
    if (l == 0) { redBuf[w][0] = (double)cm; redBuf[w][1] = (double)uu; }
    __syncthreads();
    if (tid == 0) {
        double c = redBuf[0][0] + redBuf[1][0] + redBuf[2][0] + redBuf[3][0];
        double u = redBuf[0][1] + redBuf[1][1] + redBuf[2][1] + redBuf[3][1];
        atomicAdd(&lossAcc[0], c);
        atomicAdd(&lossAcc[1], u);
    }
}

// prep: loss reset, C = np_sumsq (ref-exact), bf16 hi/lo frag tables (pre-scaled x2)
__global__ void rvq_prep(const float* __restrict__ cb, float* __restrict__ e2g,
                         uint4* __restrict__ hiT, uint4* __restrict__ loT,
                         double* __restrict__ lossAcc)
{
    int idx = blockIdx.x * 256 + threadIdx.x;      // 0..65535
    if (idx == 0) { lossAcc[0] = 0.0; lossAcc[1] = 0.0; }
    if (idx < NLEV * KCB)
        e2g[idx] = np_sumsq128(cb + (size_t)idx * DIMD);

    int lev = idx >> 14, rem = idx & 16383;
    int cg = rem >> 8, ks = (rem >> 6) & 3, lane = rem & 63;
    int col = cg * 16 + (lane & 15);
    int k0  = ks * 32 + (lane >> 4) * 8;
    const float* src = cb + ((size_t)lev * KCB + col) * DIMD + k0;
    unsigned hb[8], lb[8];
    #pragma unroll
    for (int e = 0; e < 8; ++e) {
        float wv = 2.0f * src[e];                  // exact scale
        unsigned b = __float_as_uint(wv);
        hb[e] = b >> 16;
        float lv = wv - __uint_as_float(b & 0xFFFF0000u);
        lb[e] = __float_as_uint(lv) >> 16;
    }
    uint4 hp, lp;
    hp.x = hb[0] | (hb[1] << 16); hp.y = hb[2] | (hb[3] << 16);
    hp.z = hb[4] | (hb[5] << 16); hp.w = hb[6] | (hb[7] << 16);
    lp.x = lb[0] | (lb[1] << 16); lp.y = lb[2] | (lb[3] << 16);
    lp.z = lb[4] | (lb[5] << 16); lp.w = lb[6] | (lb[7] << 16);
    hiT[idx] = hp;
    loT[idx] = lp;
}

__global__ void rvq_fin(const double* __restrict__ lossAcc, float* __restrict__ out)
{
    out[(size_t)NROWS * DIMD + (size_t)NROWS * NLEV] =
        (float)(lossAcc[0] * (1.25 / ((double)NROWS * (double)DIMD)));
    out[(size_t)NROWS * DIMD + (size_t)NROWS * NLEV + 1] =
        (float)(lossAcc[1] / (double)NROWS);
}

extern "C" void kernel_launch(void* const* d_in, const int* in_sizes, int n_in,
                              void* d_out, int out_size, void* d_ws, size_t ws_size,
                              hipStream_t stream)
{
    const float* x  = (const float*)d_in[0];
    const float* cb = (const float*)d_in[1];
    float* out = (float*)d_out;
    double* lossAcc = (double*)d_ws;
    float* e2g = (float*)((char*)d_ws + WS_E2G);
    uint4* hiT = (uint4*)((char*)d_ws + WS_HIT);
    uint4* loT = (uint4*)((char*)d_ws + WS_LOT);

    rvq_prep<<<dim3(256), dim3(256), 0, stream>>>(cb, e2g, hiT, loT, lossAcc);
    rvq_main<<<dim3(NROWS / 128), dim3(256), 0, stream>>>(x, cb, out, e2g, hiT, loT, lossAcc);
    rvq_fin<<<dim3(1), dim3(1), 0, stream>>>(lossAcc, out);
}